// Round 3
// baseline (3309.922 us; speedup 1.0000x reference)
//
#include <hip/hip_runtime.h>
#include <math.h>

// MultiHeadAttention: B=4,S=2048,D=1024,H=16,DK=64
// Round 3: output dtype fix — inputs are fp32 (confirmed by round-1 NaN +
// round-2 sniffer flip), output must be fp32 too (round-2 absmax 7.72 is the
// exact signature of bf16-packed writes into an fp32 buffer: first half
// ~|ref_i - ref_{i+1}|, second half untouched-zero ~max|ref|).
//  - stage 1: proj_kernel   q/k/v = X @ W[h]   -> ws fp32 [B,H,S,DK]
//  - stage 2: attn_kernel   causal flash softmax(q k^T * 8) v -> ws fp32 [B,S,D]
//  - stage 3: outproj_kernel concat @ Wo^T + bo -> fp32 d_out
// dtype sniffer kept as cheap insurance (handles bf16 or fp32 inputs).

#define BB 4
#define SS 2048
#define DD 1024
#define HH 16
#define DKK 64
#define MM (BB * SS) // 8192

typedef unsigned short u16;

__device__ __forceinline__ float bf2f(u16 u) {
    union { unsigned int i; float f; } c;
    c.i = ((unsigned int)u) << 16;
    return c.f;
}

// ---------------- stage 0: dtype sniffer ----------------
// flag=1 => fp32. bf16 N(0,sigma) data never has exponent >=0xF0 or
// nonzero <=0x0F; fp32 mantissa halves do ~12.5% of the time.
__global__ void sniff_kernel(const u16* t0, const u16* t1, const u16* t2,
                             const u16* t3, const u16* t4, const u16* t5,
                             const u16* t6, const u16* t7, int* flags)
{
    const u16* ptrs[8] = {t0, t1, t2, t3, t4, t5, t6, t7};
    const u16* p = ptrs[blockIdx.x];
    int tid = threadIdx.x; // 64 threads
    int cnt = 0;
    #pragma unroll
    for (int i = 0; i < 8; i++) {
        u16 v = p[tid * 8 + i];
        int e = (v >> 7) & 0xFF;
        if (e >= 0xF0 || (e <= 0x0F && (v & 0x7FFF) != 0)) cnt++;
    }
    #pragma unroll
    for (int off = 32; off; off >>= 1) cnt += __shfl_down(cnt, off);
    if (tid == 0) flags[blockIdx.x] = (cnt >= 4) ? 1 : 0;
}

// ---------------- stage 1: per-head projections ----------------
// grid: (MM/64, H, 3), block 256.  64(M) x 64(N=DK) tile, K=1024.
__global__ __launch_bounds__(256) void proj_kernel(
    const void* __restrict__ Q, const void* __restrict__ K, const void* __restrict__ V,
    const void* __restrict__ Wq, const void* __restrict__ Wk, const void* __restrict__ Wv,
    const int* __restrict__ flags,
    float* __restrict__ qb, float* __restrict__ kb, float* __restrict__ vb)
{
    const int z = blockIdx.z;
    const void* __restrict__ X = (z == 0) ? Q : (z == 1) ? K : V;
    const void* __restrict__ W = (z == 0) ? Wq : (z == 1) ? Wk : Wv;
    float* __restrict__ out    = (z == 0) ? qb : (z == 1) ? kb : vb;
    const int xf = flags[z];      // 1 => fp32
    const int wf = flags[3 + z];
    const int h  = blockIdx.y;
    const int m0 = blockIdx.x * 64;

    __shared__ float Xs[32][68]; // [k][m]
    __shared__ float Ws[32][64]; // [k][n]

    const int tid = threadIdx.x;
    const int tx = tid & 15, ty = tid >> 4;
    const int xk4 = tid & 7, xrow = tid >> 3;
    const int wn = tid & 63, wk = tid >> 6;

    float acc[4][4] = {};

    for (int kbase = 0; kbase < DD; kbase += 32) {
        __syncthreads();
        if (xf) {
            const float* Xf = (const float*)X;
            #pragma unroll
            for (int half = 0; half < 2; half++) {
                int m = m0 + half * 32 + xrow;
                float4 v4 = *(const float4*)(Xf + m * DD + kbase + xk4 * 4);
                Xs[xk4 * 4 + 0][half * 32 + xrow] = v4.x;
                Xs[xk4 * 4 + 1][half * 32 + xrow] = v4.y;
                Xs[xk4 * 4 + 2][half * 32 + xrow] = v4.z;
                Xs[xk4 * 4 + 3][half * 32 + xrow] = v4.w;
            }
        } else {
            const u16* Xb = (const u16*)X;
            #pragma unroll
            for (int half = 0; half < 2; half++) {
                int m = m0 + half * 32 + xrow;
                ushort4 v4 = *(const ushort4*)(Xb + m * DD + kbase + xk4 * 4);
                Xs[xk4 * 4 + 0][half * 32 + xrow] = bf2f(v4.x);
                Xs[xk4 * 4 + 1][half * 32 + xrow] = bf2f(v4.y);
                Xs[xk4 * 4 + 2][half * 32 + xrow] = bf2f(v4.z);
                Xs[xk4 * 4 + 3][half * 32 + xrow] = bf2f(v4.w);
            }
        }
        if (wf) {
            const float* Wf = (const float*)W;
            #pragma unroll
            for (int p = 0; p < 8; p++) {
                int kk = p * 4 + wk;
                Ws[kk][wn] = Wf[h * DD * DKK + (kbase + kk) * DKK + wn];
            }
        } else {
            const u16* Wb = (const u16*)W;
            #pragma unroll
            for (int p = 0; p < 8; p++) {
                int kk = p * 4 + wk;
                Ws[kk][wn] = bf2f(Wb[h * DD * DKK + (kbase + kk) * DKK + wn]);
            }
        }
        __syncthreads();
        #pragma unroll
        for (int kk = 0; kk < 32; kk++) {
            float4 xa = *(const float4*)&Xs[kk][ty * 4];
            float4 wb = *(const float4*)&Ws[kk][tx * 4];
            float xv[4] = {xa.x, xa.y, xa.z, xa.w};
            float wv[4] = {wb.x, wb.y, wb.z, wb.w};
            #pragma unroll
            for (int i = 0; i < 4; i++)
                #pragma unroll
                for (int j = 0; j < 4; j++)
                    acc[i][j] += xv[i] * wv[j];
        }
    }
    #pragma unroll
    for (int i = 0; i < 4; i++) {
        int m = m0 + ty * 4 + i;
        int b = m / SS, s = m % SS;
        float4 r = make_float4(acc[i][0], acc[i][1], acc[i][2], acc[i][3]);
        *(float4*)&out[(((b * HH + h) * SS + s)) * DKK + tx * 4] = r;
    }
}

// ---------------- stage 2: causal flash attention ----------------
// grid: (S/128, B*H), block 128.  1 thread = 1 query row; 64-key tiles in LDS.
__global__ __launch_bounds__(128) void attn_kernel(
    const float* __restrict__ qb, const float* __restrict__ kb,
    const float* __restrict__ vb, float* __restrict__ cat)
{
    const int bh = blockIdx.y;
    const int b = bh >> 4;
    const int h = bh & 15;
    const int qrow = blockIdx.x * 128 + threadIdx.x;

    __shared__ float Ks[64 * 64];
    __shared__ float Vs[64 * 64];

    const float* qp = qb + (bh * SS + qrow) * DKK;
    float4 q4[16];
    #pragma unroll
    for (int t = 0; t < 16; t++) q4[t] = ((const float4*)qp)[t];

    float acc[64];
    #pragma unroll
    for (int d = 0; d < 64; d++) acc[d] = 0.f;
    float m = -INFINITY, l = 0.f;

    const int ntiles = blockIdx.x * 2 + 2;

    for (int kt = 0; kt < ntiles; kt++) {
        __syncthreads();
        {
            const float4* ksrc = (const float4*)(kb + (bh * SS + kt * 64) * DKK);
            const float4* vsrc = (const float4*)(vb + (bh * SS + kt * 64) * DKK);
            float4* kdst = (float4*)Ks;
            float4* vdst = (float4*)Vs;
            #pragma unroll
            for (int p = 0; p < 8; p++) {
                kdst[p * 128 + threadIdx.x] = ksrc[p * 128 + threadIdx.x];
                vdst[p * 128 + threadIdx.x] = vsrc[p * 128 + threadIdx.x];
            }
        }
        __syncthreads();
        const int lim = qrow - kt * 64;

        for (int c = 0; c < 8; c++) {
            float sc8[8];
            #pragma unroll
            for (int j2 = 0; j2 < 8; j2++) {
                int j = c * 8 + j2;
                const float4* kr = (const float4*)(Ks + j * 64);
                float s = 0.f;
                #pragma unroll
                for (int t = 0; t < 16; t++) {
                    float4 kv = kr[t];
                    s += q4[t].x * kv.x + q4[t].y * kv.y + q4[t].z * kv.z + q4[t].w * kv.w;
                }
                s *= 8.0f; // scale = DK/sqrt(DK)
                sc8[j2] = (j <= lim) ? s : -INFINITY;
            }
            float cmax = sc8[0];
            #pragma unroll
            for (int j2 = 1; j2 < 8; j2++) cmax = fmaxf(cmax, sc8[j2]);
            float mnew = fmaxf(m, cmax);
            float alpha = __expf(m - mnew);
            l *= alpha;
            #pragma unroll
            for (int d = 0; d < 64; d++) acc[d] *= alpha;
            m = mnew;
            #pragma unroll
            for (int j2 = 0; j2 < 8; j2++) {
                float w = __expf(sc8[j2] - m);
                l += w;
                int j = c * 8 + j2;
                const float4* vr = (const float4*)(Vs + j * 64);
                #pragma unroll
                for (int t = 0; t < 16; t++) {
                    float4 vv = vr[t];
                    acc[t * 4 + 0] += w * vv.x;
                    acc[t * 4 + 1] += w * vv.y;
                    acc[t * 4 + 2] += w * vv.z;
                    acc[t * 4 + 3] += w * vv.w;
                }
            }
        }
    }
    float inv = 1.0f / l;
    float* op = cat + (b * SS + qrow) * DD + h * DKK;
    #pragma unroll
    for (int t = 0; t < 16; t++) {
        float4 r = make_float4(acc[t * 4] * inv, acc[t * 4 + 1] * inv,
                               acc[t * 4 + 2] * inv, acc[t * 4 + 3] * inv);
        ((float4*)op)[t] = r;
    }
}

// ---------------- stage 3: output projection (fp32 out) ----------------
__global__ __launch_bounds__(256) void outproj_kernel(
    const float* __restrict__ A, const void* __restrict__ Wo,
    const void* __restrict__ bo, const int* __restrict__ flags,
    float* __restrict__ out)
{
    const int wf = flags[6]; // Wo
    const int bf = flags[7]; // bo
    const int m0 = blockIdx.x * 64;
    const int n0 = blockIdx.y * 64;
    __shared__ float As[32][68];
    __shared__ float Bs[32][68];

    const int tid = threadIdx.x;
    const int tx = tid & 15, ty = tid >> 4;
    const int k4 = tid & 7, row = tid >> 3;

    float acc[4][4] = {};

    for (int kbase = 0; kbase < DD; kbase += 32) {
        __syncthreads();
        #pragma unroll
        for (int half = 0; half < 2; half++) {
            int mm = m0 + half * 32 + row;
            float4 a4 = *(const float4*)&A[mm * DD + kbase + k4 * 4];
            As[k4 * 4 + 0][half * 32 + row] = a4.x;
            As[k4 * 4 + 1][half * 32 + row] = a4.y;
            As[k4 * 4 + 2][half * 32 + row] = a4.z;
            As[k4 * 4 + 3][half * 32 + row] = a4.w;
            int nn = n0 + half * 32 + row;
            if (wf) {
                float4 w4 = *(const float4*)((const float*)Wo + nn * DD + kbase + k4 * 4);
                Bs[k4 * 4 + 0][half * 32 + row] = w4.x;
                Bs[k4 * 4 + 1][half * 32 + row] = w4.y;
                Bs[k4 * 4 + 2][half * 32 + row] = w4.z;
                Bs[k4 * 4 + 3][half * 32 + row] = w4.w;
            } else {
                ushort4 w4 = *(const ushort4*)((const u16*)Wo + nn * DD + kbase + k4 * 4);
                Bs[k4 * 4 + 0][half * 32 + row] = bf2f(w4.x);
                Bs[k4 * 4 + 1][half * 32 + row] = bf2f(w4.y);
                Bs[k4 * 4 + 2][half * 32 + row] = bf2f(w4.z);
                Bs[k4 * 4 + 3][half * 32 + row] = bf2f(w4.w);
            }
        }
        __syncthreads();
        #pragma unroll
        for (int kk = 0; kk < 32; kk++) {
            float4 xa = *(const float4*)&As[kk][ty * 4];
            float4 wb = *(const float4*)&Bs[kk][tx * 4];
            float xv[4] = {xa.x, xa.y, xa.z, xa.w};
            float wv[4] = {wb.x, wb.y, wb.z, wb.w};
            #pragma unroll
            for (int i = 0; i < 4; i++)
                #pragma unroll
                for (int j = 0; j < 4; j++)
                    acc[i][j] += xv[i] * wv[j];
        }
    }
    float bias[4];
    #pragma unroll
    for (int j = 0; j < 4; j++) {
        int n = n0 + tx * 4 + j;
        bias[j] = bf ? ((const float*)bo)[n] : bf2f(((const u16*)bo)[n]);
    }
    #pragma unroll
    for (int i = 0; i < 4; i++) {
        int mm = m0 + ty * 4 + i;
        float4 st = make_float4(acc[i][0] + bias[0], acc[i][1] + bias[1],
                                acc[i][2] + bias[2], acc[i][3] + bias[3]);
        *(float4*)&out[mm * DD + n0 + tx * 4] = st;
    }
}

extern "C" void kernel_launch(void* const* d_in, const int* in_sizes, int n_in,
                              void* d_out, int out_size, void* d_ws, size_t ws_size,
                              hipStream_t stream)
{
    const void* Q = d_in[0];
    const void* K = d_in[1];
    const void* V = d_in[2];
    // mask (bool tril) present iff n_in >= 9; ignored either way (causal
    // masking applied analytically).
    const int widx = (n_in >= 9) ? 4 : 3;
    const void* Wq = d_in[widx + 0];
    const void* Wk = d_in[widx + 1];
    const void* Wv = d_in[widx + 2];
    const void* Wo = d_in[widx + 3];
    const void* bo = d_in[widx + 4];
    float* out = (float*)d_out;

    const size_t per = (size_t)BB * HH * SS * DKK; // 8,388,608 floats
    float* qb  = (float*)d_ws;
    float* kb  = qb + per;
    float* vb  = kb + per;
    float* cat = vb + per;
    int* flags = (int*)(cat + per);

    sniff_kernel<<<8, 64, 0, stream>>>(
        (const u16*)Q, (const u16*)K, (const u16*)V,
        (const u16*)Wq, (const u16*)Wk, (const u16*)Wv,
        (const u16*)Wo, (const u16*)bo, flags);

    dim3 g1(MM / 64, HH, 3);
    proj_kernel<<<g1, 256, 0, stream>>>(Q, K, V, Wq, Wk, Wv, flags, qb, kb, vb);

    dim3 g2(SS / 128, BB * HH);
    attn_kernel<<<g2, 128, 0, stream>>>(qb, kb, vb, cat);

    dim3 g3(MM / 64, DD / 64);
    outproj_kernel<<<g3, 256, 0, stream>>>(cat, Wo, bo, flags, out);
}

// Round 5
// 1311.975 us; speedup vs baseline: 2.5229x; 2.5229x over previous
//
#include <hip/hip_runtime.h>
#include <math.h>

// MultiHeadAttention: B=4,S=2048,D=1024,H=16,DK=64
// Round 5: fp16 MFMA flash attention. Round-4 bf16 failed at absmax 0.293 =
// logit-noise signature (sigma_logit=64, bf16 eps -> ~0.2 logit noise ->
// near-tie softmax flips). fp16 = 8x less noise -> predicted absmax ~0.04.
//   stage 1: proj (fp32 vector GEMM) -> fp16 q/k/v [B,H,S,DK]
//   stage 2: attn  4 waves/block, 64 q-rows/block, 64-key LDS tiles,
//            QK^T f16-mfma -> online softmax -> P (fp16, l from rounded P)
//            via per-wave LDS roundtrip -> PV f16-mfma
//   stage 3: outproj (fp32 vector GEMM) -> fp32 d_out

#define BB 4
#define SS 2048
#define DD 1024
#define HH 16
#define DKK 64
#define MM (BB * SS) // 8192

typedef unsigned short u16;
typedef _Float16 f16x8 __attribute__((ext_vector_type(8)));
typedef float f32x4 __attribute__((ext_vector_type(4)));

__device__ __forceinline__ float bf2f(u16 u) {
    union { unsigned int i; float f; } c;
    c.i = ((unsigned int)u) << 16;
    return c.f;
}
__device__ __forceinline__ u16 f2h(float f) {
    _Float16 h = (_Float16)f; // RNE
    return __builtin_bit_cast(u16, h);
}

// ---------------- stage 0: dtype sniffer (insurance) ----------------
__global__ void sniff_kernel(const u16* t0, const u16* t1, const u16* t2,
                             const u16* t3, const u16* t4, const u16* t5,
                             const u16* t6, const u16* t7, int* flags)
{
    const u16* ptrs[8] = {t0, t1, t2, t3, t4, t5, t6, t7};
    const u16* p = ptrs[blockIdx.x];
    int tid = threadIdx.x; // 64
    int cnt = 0;
    #pragma unroll
    for (int i = 0; i < 8; i++) {
        u16 v = p[tid * 8 + i];
        int e = (v >> 7) & 0xFF;
        if (e >= 0xF0 || (e <= 0x0F && (v & 0x7FFF) != 0)) cnt++;
    }
    #pragma unroll
    for (int off = 32; off; off >>= 1) cnt += __shfl_down(cnt, off);
    if (tid == 0) flags[blockIdx.x] = (cnt >= 4) ? 1 : 0;
}

// ---------------- stage 1: per-head projections -> fp16 ----------------
// grid: (MM/64, H, 3), block 256.  64(M) x 64(N=DK) tile, K=1024.
__global__ __launch_bounds__(256) void proj_kernel(
    const void* __restrict__ Q, const void* __restrict__ K, const void* __restrict__ V,
    const void* __restrict__ Wq, const void* __restrict__ Wk, const void* __restrict__ Wv,
    const int* __restrict__ flags,
    u16* __restrict__ qb, u16* __restrict__ kb, u16* __restrict__ vb)
{
    const int z = blockIdx.z;
    const void* __restrict__ X = (z == 0) ? Q : (z == 1) ? K : V;
    const void* __restrict__ W = (z == 0) ? Wq : (z == 1) ? Wk : Wv;
    u16* __restrict__ out      = (z == 0) ? qb : (z == 1) ? kb : vb;
    const int xf = flags[z];
    const int wf = flags[3 + z];
    const int h  = blockIdx.y;
    const int m0 = blockIdx.x * 64;

    __shared__ float Xs[32][68];
    __shared__ float Ws[32][64];

    const int tid = threadIdx.x;
    const int tx = tid & 15, ty = tid >> 4;
    const int xk4 = tid & 7, xrow = tid >> 3;
    const int wn = tid & 63, wk = tid >> 6;

    float acc[4][4] = {};

    for (int kbase = 0; kbase < DD; kbase += 32) {
        __syncthreads();
        if (xf) {
            const float* Xf = (const float*)X;
            #pragma unroll
            for (int half = 0; half < 2; half++) {
                int m = m0 + half * 32 + xrow;
                float4 v4 = *(const float4*)(Xf + m * DD + kbase + xk4 * 4);
                Xs[xk4 * 4 + 0][half * 32 + xrow] = v4.x;
                Xs[xk4 * 4 + 1][half * 32 + xrow] = v4.y;
                Xs[xk4 * 4 + 2][half * 32 + xrow] = v4.z;
                Xs[xk4 * 4 + 3][half * 32 + xrow] = v4.w;
            }
        } else {
            const u16* Xb = (const u16*)X;
            #pragma unroll
            for (int half = 0; half < 2; half++) {
                int m = m0 + half * 32 + xrow;
                ushort4 v4 = *(const ushort4*)(Xb + m * DD + kbase + xk4 * 4);
                Xs[xk4 * 4 + 0][half * 32 + xrow] = bf2f(v4.x);
                Xs[xk4 * 4 + 1][half * 32 + xrow] = bf2f(v4.y);
                Xs[xk4 * 4 + 2][half * 32 + xrow] = bf2f(v4.z);
                Xs[xk4 * 4 + 3][half * 32 + xrow] = bf2f(v4.w);
            }
        }
        if (wf) {
            const float* Wf = (const float*)W;
            #pragma unroll
            for (int p = 0; p < 8; p++) {
                int kk = p * 4 + wk;
                Ws[kk][wn] = Wf[h * DD * DKK + (kbase + kk) * DKK + wn];
            }
        } else {
            const u16* Wb = (const u16*)W;
            #pragma unroll
            for (int p = 0; p < 8; p++) {
                int kk = p * 4 + wk;
                Ws[kk][wn] = bf2f(Wb[h * DD * DKK + (kbase + kk) * DKK + wn]);
            }
        }
        __syncthreads();
        #pragma unroll
        for (int kk = 0; kk < 32; kk++) {
            float4 xa = *(const float4*)&Xs[kk][ty * 4];
            float4 wb = *(const float4*)&Ws[kk][tx * 4];
            float xv[4] = {xa.x, xa.y, xa.z, xa.w};
            float wv[4] = {wb.x, wb.y, wb.z, wb.w};
            #pragma unroll
            for (int i = 0; i < 4; i++)
                #pragma unroll
                for (int j = 0; j < 4; j++)
                    acc[i][j] += xv[i] * wv[j];
        }
    }
    #pragma unroll
    for (int i = 0; i < 4; i++) {
        int m = m0 + ty * 4 + i;
        int b = m / SS, s = m % SS;
        ushort4 st;
        st.x = f2h(acc[i][0]);
        st.y = f2h(acc[i][1]);
        st.z = f2h(acc[i][2]);
        st.w = f2h(acc[i][3]);
        *(ushort4*)&out[(((size_t)(b * HH + h) * SS + s)) * DKK + tx * 4] = st;
    }
}

// ---------------- stage 2: fp16 MFMA flash attention ----------------
// grid: (S/64, B*H), block 256 (4 waves). Wave w handles q rows
// qbase+16w..+15. K tile [64key][64dk] and V^T tile [64dk][64key] in LDS,
// row stride 72 u16 (144B: 16B-aligned b128 rows, <=2-way banks).
__global__ __launch_bounds__(256) void attn_kernel(
    const u16* __restrict__ qb, const u16* __restrict__ kb,
    const u16* __restrict__ vb, float* __restrict__ cat)
{
    __shared__ __align__(16) u16 Kt[64 * 72];
    __shared__ __align__(16) u16 Vt[64 * 72];
    __shared__ __align__(16) u16 Pw[4][16 * 72];

    const int tid  = threadIdx.x;
    const int lane = tid & 63, wave = tid >> 6;
    const int quad = lane >> 4, ln = lane & 15;
    const int xt = (SS / 64 - 1) - blockIdx.x; // heavy tiles first
    const int bh = blockIdx.y;
    const int qbase = xt * 64;

    // Q A-fragments (m = ln), resident for whole kernel
    const u16* qp = qb + ((size_t)bh * SS + qbase + wave * 16 + ln) * DKK;
    f16x8 qf0 = __builtin_bit_cast(f16x8, *(const uint4*)(qp + quad * 8));
    f16x8 qf1 = __builtin_bit_cast(f16x8, *(const uint4*)(qp + 32 + quad * 8));

    f32x4 acc[4];
    #pragma unroll
    for (int n = 0; n < 4; n++) acc[n] = (f32x4){0.f, 0.f, 0.f, 0.f};
    float mrow[4], lrow[4];
    #pragma unroll
    for (int r = 0; r < 4; r++) { mrow[r] = -INFINITY; lrow[r] = 0.f; }

    const int skey = tid >> 2, sseg = (tid & 3) * 16;  // K stage
    const int vkey = tid & 63, vdkb = (tid >> 6) * 16; // V transpose stage

    for (int kt = 0; kt <= xt; ++kt) {
        __syncthreads();
        {
            const u16* ksrc = kb + ((size_t)bh * SS + kt * 64 + skey) * DKK + sseg;
            uint4 a = *(const uint4*)ksrc;
            uint4 b = *(const uint4*)(ksrc + 8);
            *(uint4*)&Kt[skey * 72 + sseg] = a;
            *(uint4*)&Kt[skey * 72 + sseg + 8] = b;

            const u16* vsrc = vb + ((size_t)bh * SS + kt * 64 + vkey) * DKK + vdkb;
            u16 vv[16];
            *(uint4*)&vv[0] = *(const uint4*)vsrc;
            *(uint4*)&vv[8] = *(const uint4*)(vsrc + 8);
            #pragma unroll
            for (int i = 0; i < 16; i++)
                Vt[(vdkb + i) * 72 + vkey] = vv[i];
        }
        __syncthreads();

        // ---- S = Q K^T (16 q-rows x 64 keys), 8 MFMAs ----
        f32x4 sa[4];
        #pragma unroll
        for (int n = 0; n < 4; n++) {
            sa[n] = (f32x4){0.f, 0.f, 0.f, 0.f};
            f16x8 kf0 = __builtin_bit_cast(f16x8,
                *(const uint4*)&Kt[(n * 16 + ln) * 72 + quad * 8]);
            sa[n] = __builtin_amdgcn_mfma_f32_16x16x32_f16(qf0, kf0, sa[n], 0, 0, 0);
            f16x8 kf1 = __builtin_bit_cast(f16x8,
                *(const uint4*)&Kt[(n * 16 + ln) * 72 + 32 + quad * 8]);
            sa[n] = __builtin_amdgcn_mfma_f32_16x16x32_f16(qf1, kf1, sa[n], 0, 0, 0);
        }

        // ---- scale + causal mask (diagonal tile only) ----
        float sc[4][4];
        const bool diag = (kt == xt);
        #pragma unroll
        for (int n = 0; n < 4; n++)
            #pragma unroll
            for (int r = 0; r < 4; r++) {
                float s = sa[n][r] * 8.0f; // scale = DK/sqrt(DK)
                if (diag && (n * 16 + ln) > (wave * 16 + quad * 4 + r))
                    s = -INFINITY;
                sc[n][r] = s;
            }

        // ---- online softmax (row r = quad*4+r, 16 lanes/quad share row) ----
        float rmax[4];
        #pragma unroll
        for (int r = 0; r < 4; r++)
            rmax[r] = fmaxf(fmaxf(sc[0][r], sc[1][r]), fmaxf(sc[2][r], sc[3][r]));
        #pragma unroll
        for (int off = 1; off < 16; off <<= 1)
            #pragma unroll
            for (int r = 0; r < 4; r++)
                rmax[r] = fmaxf(rmax[r], __shfl_xor(rmax[r], off));
        float alpha[4];
        #pragma unroll
        for (int r = 0; r < 4; r++) {
            float mn = fmaxf(mrow[r], rmax[r]);
            alpha[r] = __expf(mrow[r] - mn);
            mrow[r] = mn;
        }
        // P rounded to fp16; l accumulated from the ROUNDED values so the
        // normalization exactly matches the PV numerator.
        u16* pw = Pw[wave];
        float lsum[4] = {0.f, 0.f, 0.f, 0.f};
        #pragma unroll
        for (int n = 0; n < 4; n++)
            #pragma unroll
            for (int r = 0; r < 4; r++) {
                float p = __expf(sc[n][r] - mrow[r]);
                _Float16 ph = (_Float16)p;
                pw[(quad * 4 + r) * 72 + n * 16 + ln] = __builtin_bit_cast(u16, ph);
                lsum[r] += (float)ph;
            }
        #pragma unroll
        for (int off = 1; off < 16; off <<= 1)
            #pragma unroll
            for (int r = 0; r < 4; r++)
                lsum[r] += __shfl_xor(lsum[r], off);
        #pragma unroll
        for (int r = 0; r < 4; r++)
            lrow[r] = lrow[r] * alpha[r] + lsum[r];
        #pragma unroll
        for (int n = 0; n < 4; n++)
            #pragma unroll
            for (int r = 0; r < 4; r++)
                acc[n][r] *= alpha[r];

        // ---- P: C-layout -> A-layout via per-wave LDS roundtrip ----
        asm volatile("s_waitcnt lgkmcnt(0)" ::: "memory"); // wave-local RAW
        f16x8 pf0 = __builtin_bit_cast(f16x8, *(const uint4*)&pw[ln * 72 + quad * 8]);
        f16x8 pf1 = __builtin_bit_cast(f16x8, *(const uint4*)&pw[ln * 72 + 32 + quad * 8]);

        // ---- O += P V (16 q-rows x 64 dk), 8 MFMAs ----
        #pragma unroll
        for (int n = 0; n < 4; n++) {
            f16x8 vf0 = __builtin_bit_cast(f16x8,
                *(const uint4*)&Vt[(n * 16 + ln) * 72 + quad * 8]);
            acc[n] = __builtin_amdgcn_mfma_f32_16x16x32_f16(pf0, vf0, acc[n], 0, 0, 0);
            f16x8 vf1 = __builtin_bit_cast(f16x8,
                *(const uint4*)&Vt[(n * 16 + ln) * 72 + 32 + quad * 8]);
            acc[n] = __builtin_amdgcn_mfma_f32_16x16x32_f16(pf1, vf1, acc[n], 0, 0, 0);
        }
    }

    // ---- epilogue: normalize, write concat layout fp32 ----
    const int b = bh >> 4, h = bh & 15;
    #pragma unroll
    for (int r = 0; r < 4; r++) {
        float inv = 1.0f / lrow[r];
        int row = qbase + wave * 16 + quad * 4 + r;
        float* op = cat + ((size_t)b * SS + row) * DD + h * DKK;
        #pragma unroll
        for (int n = 0; n < 4; n++)
            op[n * 16 + ln] = acc[n][r] * inv;
    }
}

// ---------------- stage 3: output projection (fp32 out) ----------------
__global__ __launch_bounds__(256) void outproj_kernel(
    const float* __restrict__ A, const void* __restrict__ Wo,
    const void* __restrict__ bo, const int* __restrict__ flags,
    float* __restrict__ out)
{
    const int wf = flags[6];
    const int bf = flags[7];
    const int m0 = blockIdx.x * 64;
    const int n0 = blockIdx.y * 64;
    __shared__ float As[32][68];
    __shared__ float Bs[32][68];

    const int tid = threadIdx.x;
    const int tx = tid & 15, ty = tid >> 4;
    const int k4 = tid & 7, row = tid >> 3;

    float acc[4][4] = {};

    for (int kbase = 0; kbase < DD; kbase += 32) {
        __syncthreads();
        #pragma unroll
        for (int half = 0; half < 2; half++) {
            int mm = m0 + half * 32 + row;
            float4 a4 = *(const float4*)&A[(size_t)mm * DD + kbase + k4 * 4];
            As[k4 * 4 + 0][half * 32 + row] = a4.x;
            As[k4 * 4 + 1][half * 32 + row] = a4.y;
            As[k4 * 4 + 2][half * 32 + row] = a4.z;
            As[k4 * 4 + 3][half * 32 + row] = a4.w;
            int nn = n0 + half * 32 + row;
            if (wf) {
                float4 w4 = *(const float4*)((const float*)Wo + (size_t)nn * DD + kbase + k4 * 4);
                Bs[k4 * 4 + 0][half * 32 + row] = w4.x;
                Bs[k4 * 4 + 1][half * 32 + row] = w4.y;
                Bs[k4 * 4 + 2][half * 32 + row] = w4.z;
                Bs[k4 * 4 + 3][half * 32 + row] = w4.w;
            } else {
                ushort4 w4 = *(const ushort4*)((const u16*)Wo + (size_t)nn * DD + kbase + k4 * 4);
                Bs[k4 * 4 + 0][half * 32 + row] = bf2f(w4.x);
                Bs[k4 * 4 + 1][half * 32 + row] = bf2f(w4.y);
                Bs[k4 * 4 + 2][half * 32 + row] = bf2f(w4.z);
                Bs[k4 * 4 + 3][half * 32 + row] = bf2f(w4.w);
            }
        }
        __syncthreads();
        #pragma unroll
        for (int kk = 0; kk < 32; kk++) {
            float4 xa = *(const float4*)&As[kk][ty * 4];
            float4 wb = *(const float4*)&Bs[kk][tx * 4];
            float xv[4] = {xa.x, xa.y, xa.z, xa.w};
            float wv[4] = {wb.x, wb.y, wb.z, wb.w};
            #pragma unroll
            for (int i = 0; i < 4; i++)
                #pragma unroll
                for (int j = 0; j < 4; j++)
                    acc[i][j] += xv[i] * wv[j];
        }
    }
    float bias[4];
    #pragma unroll
    for (int j = 0; j < 4; j++) {
        int n = n0 + tx * 4 + j;
        bias[j] = bf ? ((const float*)bo)[n] : bf2f(((const u16*)bo)[n]);
    }
    #pragma unroll
    for (int i = 0; i < 4; i++) {
        int mm = m0 + ty * 4 + i;
        float4 st = make_float4(acc[i][0] + bias[0], acc[i][1] + bias[1],
                                acc[i][2] + bias[2], acc[i][3] + bias[3]);
        *(float4*)&out[(size_t)mm * DD + n0 + tx * 4] = st;
    }
}

extern "C" void kernel_launch(void* const* d_in, const int* in_sizes, int n_in,
                              void* d_out, int out_size, void* d_ws, size_t ws_size,
                              hipStream_t stream)
{
    const void* Q = d_in[0];
    const void* K = d_in[1];
    const void* V = d_in[2];
    const int widx = (n_in >= 9) ? 4 : 3; // mask present iff n_in >= 9 (ignored)
    const void* Wq = d_in[widx + 0];
    const void* Wk = d_in[widx + 1];
    const void* Wv = d_in[widx + 2];
    const void* Wo = d_in[widx + 3];
    const void* bo = d_in[widx + 4];
    float* out = (float*)d_out;

    const size_t per = (size_t)BB * HH * SS * DKK; // 8,388,608 elements
    u16* qb = (u16*)d_ws;
    u16* kb = qb + per;
    u16* vb = kb + per;
    float* cat = (float*)(vb + per);
    int* flags = (int*)(cat + per);

    sniff_kernel<<<8, 64, 0, stream>>>(
        (const u16*)Q, (const u16*)K, (const u16*)V,
        (const u16*)Wq, (const u16*)Wk, (const u16*)Wv,
        (const u16*)Wo, (const u16*)bo, flags);

    dim3 g1(MM / 64, HH, 3);
    proj_kernel<<<g1, 256, 0, stream>>>(Q, K, V, Wq, Wk, Wv, flags, qb, kb, vb);

    dim3 g2(SS / 64, BB * HH);
    attn_kernel<<<g2, 256, 0, stream>>>(qb, kb, vb, cat);

    dim3 g3(MM / 64, DD / 64);
    outproj_kernel<<<g3, 256, 0, stream>>>(cat, Wo, bo, flags, out);
}

// Round 6
// 1150.185 us; speedup vs baseline: 2.8777x; 1.1407x over previous
//
#include <hip/hip_runtime.h>
#include <math.h>

// MultiHeadAttention: B=4,S=2048,D=1024,H=16,DK=64
// Round 6: MFMA projections with fp16 hi/lo split (fp32-accurate).
//   stage 1: proj_mfma  q/k/v = X @ W[h] via 16x16x32 f16 MFMA, 3-term split
//            (hi*Whi + hi*Wlo + lo*Whi), 128m x 64n tile/block -> fp16 q/k/v
//   stage 2: attn  fp16 MFMA flash attention (unchanged from round 5)
//   stage 3: outproj (fp32 vector GEMM, unchanged) -> fp32 d_out
// Verified 16x16x32 layouts: A[m=ln][k=quad*8+j], B-frag needs [n][k-contig]
// LDS rows, C/D col=ln, row=quad*4+r.

#define BB 4
#define SS 2048
#define DD 1024
#define HH 16
#define DKK 64
#define MM (BB * SS) // 8192

typedef unsigned short u16;
typedef _Float16 f16x8 __attribute__((ext_vector_type(8)));
typedef float f32x4 __attribute__((ext_vector_type(4)));

__device__ __forceinline__ float bf2f(u16 u) {
    union { unsigned int i; float f; } c;
    c.i = ((unsigned int)u) << 16;
    return c.f;
}
__device__ __forceinline__ u16 f2h(float f) {
    _Float16 h = (_Float16)f; // RNE
    return __builtin_bit_cast(u16, h);
}

// ---------------- stage 0: dtype sniffer (insurance) ----------------
__global__ void sniff_kernel(const u16* t0, const u16* t1, const u16* t2,
                             const u16* t3, const u16* t4, const u16* t5,
                             const u16* t6, const u16* t7, int* flags)
{
    const u16* ptrs[8] = {t0, t1, t2, t3, t4, t5, t6, t7};
    const u16* p = ptrs[blockIdx.x];
    int tid = threadIdx.x; // 64
    int cnt = 0;
    #pragma unroll
    for (int i = 0; i < 8; i++) {
        u16 v = p[tid * 8 + i];
        int e = (v >> 7) & 0xFF;
        if (e >= 0xF0 || (e <= 0x0F && (v & 0x7FFF) != 0)) cnt++;
    }
    #pragma unroll
    for (int off = 32; off; off >>= 1) cnt += __shfl_down(cnt, off);
    if (tid == 0) flags[blockIdx.x] = (cnt >= 4) ? 1 : 0;
}

// ---------------- stage 1: MFMA projections (hi/lo split) ----------------
// grid: (MM/128, H, 3), block 256 (4 waves). Wave w: rows w*32..+31.
// K-chunks of 64. LDS: Xhi/Xlo [128][72], Whi/Wlo [64n][72k] (transposed).
// k-swizzle: 8-elem group g stored at g ^ (row&7) to break staging conflicts.
__global__ __launch_bounds__(256) void proj_mfma_kernel(
    const void* __restrict__ Q, const void* __restrict__ K, const void* __restrict__ V,
    const void* __restrict__ Wq, const void* __restrict__ Wk, const void* __restrict__ Wv,
    const int* __restrict__ flags,
    u16* __restrict__ qb, u16* __restrict__ kb, u16* __restrict__ vb)
{
    const int z = blockIdx.z;
    const void* __restrict__ X = (z == 0) ? Q : (z == 1) ? K : V;
    const void* __restrict__ W = (z == 0) ? Wq : (z == 1) ? Wk : Wv;
    u16* __restrict__ out      = (z == 0) ? qb : (z == 1) ? kb : vb;
    const int xf = flags[z];
    const int wf = flags[3 + z];
    const int h  = blockIdx.y;
    const int m0 = blockIdx.x * 128;

    __shared__ __align__(16) u16 Xh[128 * 72];
    __shared__ __align__(16) u16 Xl[128 * 72];
    __shared__ __align__(16) u16 Wh[64 * 72];
    __shared__ __align__(16) u16 Wl[64 * 72];

    const int tid  = threadIdx.x;
    const int lane = tid & 63, wave = tid >> 6;
    const int quad = lane >> 4, ln = lane & 15;

    // staging maps
    const int trow = tid >> 1, tseg = (tid & 1) * 32; // X: 32 k-elems/thread
    const int wn = tid & 63, wkq = (tid >> 6) * 16;   // W: 16 k-elems/thread

    f32x4 acc[2][4];
    #pragma unroll
    for (int mh = 0; mh < 2; mh++)
        #pragma unroll
        for (int nt = 0; nt < 4; nt++)
            acc[mh][nt] = (f32x4){0.f, 0.f, 0.f, 0.f};

    for (int kbase = 0; kbase < DD; kbase += 64) {
        __syncthreads();
        // ---- stage X tile 128m x 64k -> hi/lo fp16, swizzled ----
        const int xsw = (trow & 7) << 3;
        #pragma unroll
        for (int i = 0; i < 8; i++) {
            float x4[4];
            if (xf) {
                float4 v = *(const float4*)((const float*)X +
                    (size_t)(m0 + trow) * DD + kbase + tseg + 4 * i);
                x4[0] = v.x; x4[1] = v.y; x4[2] = v.z; x4[3] = v.w;
            } else {
                ushort4 v = *(const ushort4*)((const u16*)X +
                    (size_t)(m0 + trow) * DD + kbase + tseg + 4 * i);
                x4[0] = bf2f(v.x); x4[1] = bf2f(v.y); x4[2] = bf2f(v.z); x4[3] = bf2f(v.w);
            }
            ushort4 h4, l4;
            {
                _Float16 hh;
                hh = (_Float16)x4[0]; h4.x = __builtin_bit_cast(u16, hh);
                l4.x = f2h(x4[0] - (float)hh);
                hh = (_Float16)x4[1]; h4.y = __builtin_bit_cast(u16, hh);
                l4.y = f2h(x4[1] - (float)hh);
                hh = (_Float16)x4[2]; h4.z = __builtin_bit_cast(u16, hh);
                l4.z = f2h(x4[2] - (float)hh);
                hh = (_Float16)x4[3]; h4.w = __builtin_bit_cast(u16, hh);
                l4.w = f2h(x4[3] - (float)hh);
            }
            int kcol = tseg + 4 * i;
            int kphys = (kcol & 7) | ((kcol ^ xsw) & 56);
            *(ushort4*)&Xh[trow * 72 + kphys] = h4;
            *(ushort4*)&Xl[trow * 72 + kphys] = l4;
        }
        // ---- stage W tile 64k x 64n -> transposed [n][k] hi/lo, swizzled ----
        const int wsw = (wn & 7) << 3;
        #pragma unroll
        for (int j = 0; j < 4; j++) {
            float w4[4];
            #pragma unroll
            for (int jj = 0; jj < 4; jj++) {
                int kk = kbase + wkq + 4 * j + jj;
                if (wf)
                    w4[jj] = ((const float*)W)[(size_t)h * DD * DKK + (size_t)kk * DKK + wn];
                else
                    w4[jj] = bf2f(((const u16*)W)[(size_t)h * DD * DKK + (size_t)kk * DKK + wn]);
            }
            ushort4 h4, l4;
            {
                _Float16 hh;
                hh = (_Float16)w4[0]; h4.x = __builtin_bit_cast(u16, hh);
                l4.x = f2h(w4[0] - (float)hh);
                hh = (_Float16)w4[1]; h4.y = __builtin_bit_cast(u16, hh);
                l4.y = f2h(w4[1] - (float)hh);
                hh = (_Float16)w4[2]; h4.z = __builtin_bit_cast(u16, hh);
                l4.z = f2h(w4[2] - (float)hh);
                hh = (_Float16)w4[3]; h4.w = __builtin_bit_cast(u16, hh);
                l4.w = f2h(w4[3] - (float)hh);
            }
            int kcol = wkq + 4 * j;
            int kphys = (kcol & 7) | ((kcol ^ wsw) & 56);
            *(ushort4*)&Wh[wn * 72 + kphys] = h4;
            *(ushort4*)&Wl[wn * 72 + kphys] = l4;
        }
        __syncthreads();

        // ---- compute: 2 k-halves x 4 n-tiles x 2 m-halves x 3 MFMAs ----
        #pragma unroll
        for (int kh = 0; kh < 2; kh++) {
            f16x8 ah[2], al[2];
            #pragma unroll
            for (int mh = 0; mh < 2; mh++) {
                int row = wave * 32 + mh * 16 + ln;
                int kgrp = (((kh * 4 + quad) ^ (row & 7)) << 3);
                ah[mh] = __builtin_bit_cast(f16x8, *(const uint4*)&Xh[row * 72 + kgrp]);
                al[mh] = __builtin_bit_cast(f16x8, *(const uint4*)&Xl[row * 72 + kgrp]);
            }
            #pragma unroll
            for (int nt = 0; nt < 4; nt++) {
                int n = nt * 16 + ln;
                int kgrp = (((kh * 4 + quad) ^ (n & 7)) << 3);
                f16x8 bh = __builtin_bit_cast(f16x8, *(const uint4*)&Wh[n * 72 + kgrp]);
                f16x8 bl = __builtin_bit_cast(f16x8, *(const uint4*)&Wl[n * 72 + kgrp]);
                #pragma unroll
                for (int mh = 0; mh < 2; mh++) {
                    acc[mh][nt] = __builtin_amdgcn_mfma_f32_16x16x32_f16(al[mh], bh, acc[mh][nt], 0, 0, 0);
                    acc[mh][nt] = __builtin_amdgcn_mfma_f32_16x16x32_f16(ah[mh], bl, acc[mh][nt], 0, 0, 0);
                    acc[mh][nt] = __builtin_amdgcn_mfma_f32_16x16x32_f16(ah[mh], bh, acc[mh][nt], 0, 0, 0);
                }
            }
        }
    }

    // ---- epilogue: fp16 store to [B,H,S,DK] ----
    #pragma unroll
    for (int mh = 0; mh < 2; mh++)
        #pragma unroll
        for (int r = 0; r < 4; r++) {
            int m = m0 + wave * 32 + mh * 16 + quad * 4 + r;
            int b = m >> 11, s = m & 2047;
            u16* op = out + (((size_t)(b * HH + h) * SS + s)) * DKK;
            #pragma unroll
            for (int nt = 0; nt < 4; nt++)
                op[nt * 16 + ln] = f2h(acc[mh][nt][r]);
        }
}

// ---------------- stage 2: fp16 MFMA flash attention (unchanged) ----------------
__global__ __launch_bounds__(256) void attn_kernel(
    const u16* __restrict__ qb, const u16* __restrict__ kb,
    const u16* __restrict__ vb, float* __restrict__ cat)
{
    __shared__ __align__(16) u16 Kt[64 * 72];
    __shared__ __align__(16) u16 Vt[64 * 72];
    __shared__ __align__(16) u16 Pw[4][16 * 72];

    const int tid  = threadIdx.x;
    const int lane = tid & 63, wave = tid >> 6;
    const int quad = lane >> 4, ln = lane & 15;
    const int xt = (SS / 64 - 1) - blockIdx.x; // heavy tiles first
    const int bh = blockIdx.y;
    const int qbase = xt * 64;

    const u16* qp = qb + ((size_t)bh * SS + qbase + wave * 16 + ln) * DKK;
    f16x8 qf0 = __builtin_bit_cast(f16x8, *(const uint4*)(qp + quad * 8));
    f16x8 qf1 = __builtin_bit_cast(f16x8, *(const uint4*)(qp + 32 + quad * 8));

    f32x4 acc[4];
    #pragma unroll
    for (int n = 0; n < 4; n++) acc[n] = (f32x4){0.f, 0.f, 0.f, 0.f};
    float mrow[4], lrow[4];
    #pragma unroll
    for (int r = 0; r < 4; r++) { mrow[r] = -INFINITY; lrow[r] = 0.f; }

    const int skey = tid >> 2, sseg = (tid & 3) * 16;
    const int vkey = tid & 63, vdkb = (tid >> 6) * 16;

    for (int kt = 0; kt <= xt; ++kt) {
        __syncthreads();
        {
            const u16* ksrc = kb + ((size_t)bh * SS + kt * 64 + skey) * DKK + sseg;
            uint4 a = *(const uint4*)ksrc;
            uint4 b = *(const uint4*)(ksrc + 8);
            *(uint4*)&Kt[skey * 72 + sseg] = a;
            *(uint4*)&Kt[skey * 72 + sseg + 8] = b;

            const u16* vsrc = vb + ((size_t)bh * SS + kt * 64 + vkey) * DKK + vdkb;
            u16 vv[16];
            *(uint4*)&vv[0] = *(const uint4*)vsrc;
            *(uint4*)&vv[8] = *(const uint4*)(vsrc + 8);
            #pragma unroll
            for (int i = 0; i < 16; i++)
                Vt[(vdkb + i) * 72 + vkey] = vv[i];
        }
        __syncthreads();

        f32x4 sa[4];
        #pragma unroll
        for (int n = 0; n < 4; n++) {
            sa[n] = (f32x4){0.f, 0.f, 0.f, 0.f};
            f16x8 kf0 = __builtin_bit_cast(f16x8,
                *(const uint4*)&Kt[(n * 16 + ln) * 72 + quad * 8]);
            sa[n] = __builtin_amdgcn_mfma_f32_16x16x32_f16(qf0, kf0, sa[n], 0, 0, 0);
            f16x8 kf1 = __builtin_bit_cast(f16x8,
                *(const uint4*)&Kt[(n * 16 + ln) * 72 + 32 + quad * 8]);
            sa[n] = __builtin_amdgcn_mfma_f32_16x16x32_f16(qf1, kf1, sa[n], 0, 0, 0);
        }

        float sc[4][4];
        const bool diag = (kt == xt);
        #pragma unroll
        for (int n = 0; n < 4; n++)
            #pragma unroll
            for (int r = 0; r < 4; r++) {
                float s = sa[n][r] * 8.0f;
                if (diag && (n * 16 + ln) > (wave * 16 + quad * 4 + r))
                    s = -INFINITY;
                sc[n][r] = s;
            }

        float rmax[4];
        #pragma unroll
        for (int r = 0; r < 4; r++)
            rmax[r] = fmaxf(fmaxf(sc[0][r], sc[1][r]), fmaxf(sc[2][r], sc[3][r]));
        #pragma unroll
        for (int off = 1; off < 16; off <<= 1)
            #pragma unroll
            for (int r = 0; r < 4; r++)
                rmax[r] = fmaxf(rmax[r], __shfl_xor(rmax[r], off));
        float alpha[4];
        #pragma unroll
        for (int r = 0; r < 4; r++) {
            float mn = fmaxf(mrow[r], rmax[r]);
            alpha[r] = __expf(mrow[r] - mn);
            mrow[r] = mn;
        }
        u16* pw = Pw[wave];
        float lsum[4] = {0.f, 0.f, 0.f, 0.f};
        #pragma unroll
        for (int n = 0; n < 4; n++)
            #pragma unroll
            for (int r = 0; r < 4; r++) {
                float p = __expf(sc[n][r] - mrow[r]);
                _Float16 ph = (_Float16)p;
                pw[(quad * 4 + r) * 72 + n * 16 + ln] = __builtin_bit_cast(u16, ph);
                lsum[r] += (float)ph;
            }
        #pragma unroll
        for (int off = 1; off < 16; off <<= 1)
            #pragma unroll
            for (int r = 0; r < 4; r++)
                lsum[r] += __shfl_xor(lsum[r], off);
        #pragma unroll
        for (int r = 0; r < 4; r++)
            lrow[r] = lrow[r] * alpha[r] + lsum[r];
        #pragma unroll
        for (int n = 0; n < 4; n++)
            #pragma unroll
            for (int r = 0; r < 4; r++)
                acc[n][r] *= alpha[r];

        asm volatile("s_waitcnt lgkmcnt(0)" ::: "memory"); // wave-local RAW
        f16x8 pf0 = __builtin_bit_cast(f16x8, *(const uint4*)&pw[ln * 72 + quad * 8]);
        f16x8 pf1 = __builtin_bit_cast(f16x8, *(const uint4*)&pw[ln * 72 + 32 + quad * 8]);

        #pragma unroll
        for (int n = 0; n < 4; n++) {
            f16x8 vf0 = __builtin_bit_cast(f16x8,
                *(const uint4*)&Vt[(n * 16 + ln) * 72 + quad * 8]);
            acc[n] = __builtin_amdgcn_mfma_f32_16x16x32_f16(pf0, vf0, acc[n], 0, 0, 0);
            f16x8 vf1 = __builtin_bit_cast(f16x8,
                *(const uint4*)&Vt[(n * 16 + ln) * 72 + 32 + quad * 8]);
            acc[n] = __builtin_amdgcn_mfma_f32_16x16x32_f16(pf1, vf1, acc[n], 0, 0, 0);
        }
    }

    const int b = bh >> 4, h = bh & 15;
    #pragma unroll
    for (int r = 0; r < 4; r++) {
        float inv = 1.0f / lrow[r];
        int row = qbase + wave * 16 + quad * 4 + r;
        float* op = cat + ((size_t)b * SS + row) * DD + h * DKK;
        #pragma unroll
        for (int n = 0; n < 4; n++)
            op[n * 16 + ln] = acc[n][r] * inv;
    }
}

// ---------------- stage 3: output projection (fp32 out, unchanged) ----------------
__global__ __launch_bounds__(256) void outproj_kernel(
    const float* __restrict__ A, const void* __restrict__ Wo,
    const void* __restrict__ bo, const int* __restrict__ flags,
    float* __restrict__ out)
{
    const int wf = flags[6];
    const int bf = flags[7];
    const int m0 = blockIdx.x * 64;
    const int n0 = blockIdx.y * 64;
    __shared__ float As[32][68];
    __shared__ float Bs[32][68];

    const int tid = threadIdx.x;
    const int tx = tid & 15, ty = tid >> 4;
    const int k4 = tid & 7, row = tid >> 3;

    float acc[4][4] = {};

    for (int kbase = 0; kbase < DD; kbase += 32) {
        __syncthreads();
        #pragma unroll
        for (int half = 0; half < 2; half++) {
            int mm = m0 + half * 32 + row;
            float4 a4 = *(const float4*)&A[(size_t)mm * DD + kbase + k4 * 4];
            As[k4 * 4 + 0][half * 32 + row] = a4.x;
            As[k4 * 4 + 1][half * 32 + row] = a4.y;
            As[k4 * 4 + 2][half * 32 + row] = a4.z;
            As[k4 * 4 + 3][half * 32 + row] = a4.w;
            int nn = n0 + half * 32 + row;
            if (wf) {
                float4 w4 = *(const float4*)((const float*)Wo + (size_t)nn * DD + kbase + k4 * 4);
                Bs[k4 * 4 + 0][half * 32 + row] = w4.x;
                Bs[k4 * 4 + 1][half * 32 + row] = w4.y;
                Bs[k4 * 4 + 2][half * 32 + row] = w4.z;
                Bs[k4 * 4 + 3][half * 32 + row] = w4.w;
            } else {
                ushort4 w4 = *(const ushort4*)((const u16*)Wo + (size_t)nn * DD + kbase + k4 * 4);
                Bs[k4 * 4 + 0][half * 32 + row] = bf2f(w4.x);
                Bs[k4 * 4 + 1][half * 32 + row] = bf2f(w4.y);
                Bs[k4 * 4 + 2][half * 32 + row] = bf2f(w4.z);
                Bs[k4 * 4 + 3][half * 32 + row] = bf2f(w4.w);
            }
        }
        __syncthreads();
        #pragma unroll
        for (int kk = 0; kk < 32; kk++) {
            float4 xa = *(const float4*)&As[kk][ty * 4];
            float4 wb = *(const float4*)&Bs[kk][tx * 4];
            float xv[4] = {xa.x, xa.y, xa.z, xa.w};
            float wv[4] = {wb.x, wb.y, wb.z, wb.w};
            #pragma unroll
            for (int i = 0; i < 4; i++)
                #pragma unroll
                for (int j = 0; j < 4; j++)
                    acc[i][j] += xv[i] * wv[j];
        }
    }
    float bias[4];
    #pragma unroll
    for (int j = 0; j < 4; j++) {
        int n = n0 + tx * 4 + j;
        bias[j] = bf ? ((const float*)bo)[n] : bf2f(((const u16*)bo)[n]);
    }
    #pragma unroll
    for (int i = 0; i < 4; i++) {
        int mm = m0 + ty * 4 + i;
        float4 st = make_float4(acc[i][0] + bias[0], acc[i][1] + bias[1],
                                acc[i][2] + bias[2], acc[i][3] + bias[3]);
        *(float4*)&out[(size_t)mm * DD + n0 + tx * 4] = st;
    }
}

extern "C" void kernel_launch(void* const* d_in, const int* in_sizes, int n_in,
                              void* d_out, int out_size, void* d_ws, size_t ws_size,
                              hipStream_t stream)
{
    const void* Q = d_in[0];
    const void* K = d_in[1];
    const void* V = d_in[2];
    const int widx = (n_in >= 9) ? 4 : 3; // mask present iff n_in >= 9 (ignored)
    const void* Wq = d_in[widx + 0];
    const void* Wk = d_in[widx + 1];
    const void* Wv = d_in[widx + 2];
    const void* Wo = d_in[widx + 3];
    const void* bo = d_in[widx + 4];
    float* out = (float*)d_out;

    const size_t per = (size_t)BB * HH * SS * DKK; // 8,388,608 elements
    u16* qb = (u16*)d_ws;
    u16* kb = qb + per;
    u16* vb = kb + per;
    float* cat = (float*)(vb + per);
    int* flags = (int*)(cat + per);

    sniff_kernel<<<8, 64, 0, stream>>>(
        (const u16*)Q, (const u16*)K, (const u16*)V,
        (const u16*)Wq, (const u16*)Wk, (const u16*)Wv,
        (const u16*)Wo, (const u16*)bo, flags);

    dim3 g1(MM / 128, HH, 3);
    proj_mfma_kernel<<<g1, 256, 0, stream>>>(Q, K, V, Wq, Wk, Wv, flags, qb, kb, vb);

    dim3 g2(SS / 64, BB * HH);
    attn_kernel<<<g2, 256, 0, stream>>>(qb, kb, vb, cat);

    dim3 g3(MM / 64, DD / 64);
    outproj_kernel<<<g3, 256, 0, stream>>>(cat, Wo, bo, flags, out);
}